// Round 1
// 248.659 us; speedup vs baseline: 1.0078x; 1.0078x over previous
//
#include <hip/hip_runtime.h>

#define NPIX 16384

typedef _Float16 f16;
typedef __attribute__((ext_vector_type(8))) _Float16 half8;
typedef __attribute__((ext_vector_type(8))) unsigned short ushort8;
typedef __attribute__((ext_vector_type(4))) float f32x4;   // native vec4
typedef __attribute__((ext_vector_type(2))) float f32x2;

// Load 8 consecutive floats (nontemporal), convert to half8 fragment.
__device__ inline half8 cvt8_nt(const float* __restrict__ p) {
  f32x4 a = __builtin_nontemporal_load((const f32x4*)p);
  f32x4 b = __builtin_nontemporal_load((const f32x4*)p + 1);
  half8 r;
  r[0] = (f16)a.x; r[1] = (f16)a.y; r[2] = (f16)a.z; r[3] = (f16)a.w;
  r[4] = (f16)b.x; r[5] = (f16)b.y; r[6] = (f16)b.z; r[7] = (f16)b.w;
  return r;
}
__device__ inline half8 cvt8(const float* __restrict__ p) {
  f32x4 a = *(const f32x4*)p;
  f32x4 b = *(const f32x4*)(p + 4);
  half8 r;
  r[0] = (f16)a.x; r[1] = (f16)a.y; r[2] = (f16)a.z; r[3] = (f16)a.w;
  r[4] = (f16)b.x; r[5] = (f16)b.y; r[6] = (f16)b.z; r[7] = (f16)b.w;
  return r;
}

// Transpose+convert:
//   y [16][8][NPIX] f32 + noise [16][8][NPIX] f32 -> feats[p][b][n] f16 ([NPIX][256], 8 MB)
//   noise2 [16][NPIX][8] f32                      -> n2p[p][b][dm] f16 ([NPIX][128], 4 MB)
__global__ __launch_bounds__(256) void pack_feats(
    const float* __restrict__ y,
    const float* __restrict__ nz,
    const float* __restrict__ nz2,
    f16* __restrict__ outf,
    f16* __restrict__ n2p)
{
  __shared__ f16 tile[64][258];
  const int p0 = blockIdx.x << 6;
  const int t = threadIdx.x;
  const int lane16 = t & 15;
  const int pl0 = t >> 4;
  #pragma unroll
  for (int g = 0; g < 16; ++g) {
    const int plane = g * 16 + pl0;          // plane = b*16 + n
    const int b = plane >> 4, n = plane & 15;
    const float* src = (n < 8) ? (y + (b * 8 + n) * NPIX)
                               : (nz + (b * 8 + (n - 8)) * NPIX);
    f32x4 v = __builtin_nontemporal_load((const f32x4*)(src + p0 + lane16 * 4));
    tile[lane16 * 4 + 0][plane] = (f16)v.x;
    tile[lane16 * 4 + 1][plane] = (f16)v.y;
    tile[lane16 * 4 + 2][plane] = (f16)v.z;
    tile[lane16 * 4 + 3][plane] = (f16)v.w;
  }
  // noise2 pack: wave = one b, 64 consecutive px -> 2 KB contiguous loads.
  // 16 B stores at 256 B stride merge in L2 (same block, near-in-time).
  #pragma unroll
  for (int it = 0; it < 4; ++it) {
    const int pair = it * 256 + t;           // b*64 + pl
    const int b = pair >> 6;
    const int pl = pair & 63;
    half8 v = cvt8_nt(nz2 + (size_t)(b * NPIX + p0 + pl) * 8);
    *(half8*)(n2p + (p0 + pl) * 128 + b * 8) = v;
  }
  __syncthreads();
  #pragma unroll
  for (int it = 0; it < 8; ++it) {
    const int idx = it * 256 + t;
    const int px = idx >> 5;
    const int c = idx & 31;
    ushort8 v = *(const ushort8*)&tile[px][c * 8];
    *(ushort8*)(outf + (p0 + px) * 256 + c * 8) = v;  // cached: re-read by lr_fused
  }
}

// Fused einsum + MLP. One wave per pixel; 4 waves (4 px) per block.
// einsum: D[b][m] = sum_{k,n} feats[b][nb(p,k)][n] * wmap[p][k][m][n]  (K=144 pad 160)
// MFMA f32_16x16x32_f16: A[i=lane&15][k=q*8+j], B[j=lane&15][k], D: col=lane&15, row=q*4+r.
// Then pointwise MLP on the same wave: D -> (LDS transpose, 512 B/wave) -> MLP1 -> lh
// bounce -> MLP2 -> block-staged writeout. No HBM round-trip for 'inter'.
__global__ __launch_bounds__(256, 4) void lr_fused(
    const f16*  __restrict__ feats,   // [NPIX][16][16] f16 (ws)
    const f16*  __restrict__ n2p,     // [NPIX][16][8] f16 (ws)
    const float* __restrict__ wmap,   // [NPIX][9][16][16] f32
    const int*  __restrict__ nidx,    // [NPIX][9] i32
    const float* __restrict__ w1,     // [64][24] f32
    const float* __restrict__ b1,     // [64] f32
    const float* __restrict__ w2,     // [8][64] f32
    const float* __restrict__ b2,     // [8] f32
    float* __restrict__ outp)         // [16][8][NPIX] f32
{
  __shared__ f16 tbuf[4][256];                    // per-wave einsum-D transpose
  __shared__ f16 lds_h[4][16 * 72];               // per-wave h [b][j] scratch
  __shared__ __align__(16) float stage[128][4];   // out tile [(b*8+f)][4 px]

  const int t = threadIdx.x;
  const int wv = t >> 6;
  const int l = t & 63;
  const int col = l & 15;
  const int q = l >> 4;

  const int bid = blockIdx.x;                               // [0, 4096)
  const int p0 = ((((bid & 7) << 9) + (bid >> 3)) << 2);    // XCD-slab swizzle
  const int p = p0 + wv;

  // ---- einsum phase ----
  const int n0 = (q & 1) * 8;
  const int kh = q >> 1;

  const int ps = __builtin_amdgcn_readfirstlane(p);
  int nb[9];
  #pragma unroll
  for (int k = 0; k < 9; ++k)
    nb[k] = __builtin_amdgcn_readfirstlane(nidx[ps * 9 + k]);

  half8 af[5], bfr[5];
  #pragma unroll
  for (int c = 0; c < 4; ++c) {
    const int k = 2 * c + kh;
    af[c]  = *(const half8*)(feats + nb[k] * 256 + col * 16 + n0);   // L2-hot gather
    bfr[c] = cvt8_nt(wmap + ((ps * 9 + k) * 16 + col) * 16 + n0);    // streaming, nt
  }
  af[4]  = (half8){0, 0, 0, 0, 0, 0, 0, 0};
  bfr[4] = (half8){0, 0, 0, 0, 0, 0, 0, 0};
  if (q < 2) {  // kk 128..143 (k=8); 144..159 zero pad
    af[4]  = *(const half8*)(feats + nb[8] * 256 + col * 16 + n0);
    bfr[4] = cvt8_nt(wmap + ((ps * 9 + 8) * 16 + col) * 16 + n0);
  }
  f32x4 acc = {0.f, 0.f, 0.f, 0.f};
  #pragma unroll
  for (int c = 0; c < 5; ++c)
    acc = __builtin_amdgcn_mfma_f32_16x16x32_f16(af[c], bfr[c], acc, 0, 0, 0);

  // D[b=q*4+r][m=col] -> tbuf[b*16+m] (wave-private; same layout 'inter' had)
  f16* tb = tbuf[wv];
  #pragma unroll
  for (int r = 0; r < 4; ++r)
    tb[(q * 4 + r) * 16 + col] = (f16)acc[r];

  // ---- MLP preloads (after einsum MFMAs: af/bfr live ranges are dead) ----
  half8 w1f[4];
  float b1f[4];
  #pragma unroll
  for (int jc = 0; jc < 4; ++jc) {
    w1f[jc] = (half8){0, 0, 0, 0, 0, 0, 0, 0};
    if (q < 3) w1f[jc] = cvt8(w1 + (jc * 16 + col) * 24 + q * 8);
    b1f[jc] = b1[jc * 16 + col];
  }
  half8 w2f[2] = {{0, 0, 0, 0, 0, 0, 0, 0}, {0, 0, 0, 0, 0, 0, 0, 0}};
  float b2f = 0.f;
  if (col < 8) {
    w2f[0] = cvt8(w2 + col * 64 + q * 8);
    w2f[1] = cvt8(w2 + col * 64 + 32 + q * 8);
    b2f = b2[col];
  }
  half8 n2v = (half8){0, 0, 0, 0, 0, 0, 0, 0};
  if (q == 2) n2v = *(const half8*)(n2p + p * 128 + col * 8);   // coalesced, L2-hot

  const f32x4 zero4 = {0.f, 0.f, 0.f, 0.f};

  // ---- MLP1: K=24 pad 32, N=64 ----
  half8 amlp = n2v;                                        // q==2: noise2; q==3: zero
  if (q < 2) amlp = *(const half8*)(tb + col * 16 + q * 8);  // d0..15 (wave-private LDS)

  f16* lh = lds_h[wv];
  #pragma unroll
  for (int jc = 0; jc < 4; ++jc) {
    f32x4 h4 = __builtin_amdgcn_mfma_f32_16x16x32_f16(amlp, w1f[jc], zero4, 0, 0, 0);
    #pragma unroll
    for (int r = 0; r < 4; ++r) {
      float hv = fmaxf(h4[r] + b1f[jc], 0.f);
      lh[(q * 4 + r) * 72 + jc * 16 + col] = (f16)hv;      // wave-private, no barrier
    }
  }

  // ---- MLP2: K=64, N=8 pad 16 ----
  f32x4 oacc = zero4;
  #pragma unroll
  for (int c2 = 0; c2 < 2; ++c2) {
    half8 a2 = *(const half8*)(lh + col * 72 + c2 * 32 + q * 8);
    oacc = __builtin_amdgcn_mfma_f32_16x16x32_f16(a2, w2f[c2], oacc, 0, 0, 0);
  }
  if (col < 8) {
    #pragma unroll
    for (int r = 0; r < 4; ++r) {
      const int row = q * 32 + r * 8 + col;   // b*8 + f
      stage[row][wv] = oacc[r] + b2f;
    }
  }

  __syncthreads();

  // ---- cooperative write-out: 128 rows x 4 px; 8 B stores merge in L2
  // (consecutive-p blocks live on the same XCD slab -> same L2 -> full lines to HBM)
  {
    const int row = t >> 1;
    const int h2 = (t & 1) * 2;
    f32x2 v = *(const f32x2*)&stage[row][h2];
    *(f32x2*)(outp + row * NPIX + p0 + h2) = v;
  }
}

extern "C" void kernel_launch(void* const* d_in, const int* in_sizes, int n_in,
                              void* d_out, int out_size, void* d_ws, size_t ws_size,
                              hipStream_t stream) {
  const float* y    = (const float*)d_in[0];
  const float* nz   = (const float*)d_in[1];
  const float* nz2  = (const float*)d_in[2];
  const float* wmap = (const float*)d_in[3];
  const float* w1   = (const float*)d_in[4];
  const float* b1   = (const float*)d_in[5];
  const float* w2   = (const float*)d_in[6];
  const float* b2   = (const float*)d_in[7];
  const int* nidx   = (const int*)d_in[8];
  float* outp = (float*)d_out;
  f16* feats = (f16*)d_ws;                                        // 8 MB
  f16* n2p   = (f16*)((char*)d_ws + (size_t)NPIX * 256 * 2);      // 4 MB

  hipLaunchKernelGGL(pack_feats, dim3(NPIX / 64), dim3(256), 0, stream,
                     y, nz, nz2, feats, n2p);
  hipLaunchKernelGGL(lr_fused, dim3(NPIX / 4), dim3(256), 0, stream,
                     feats, n2p, wmap, nidx, w1, b1, w2, b2, outp);
}